// Round 4
// baseline (2378.239 us; speedup 1.0000x reference)
//
#include <hip/hip_runtime.h>

namespace {

constexpr int B = 64;
constexpr int L = 2048;
constexpr int Q = 256;
constexpr int S = 26;
constexpr float EPS = 1e-16f;
constexpr size_t POST = (size_t)B * L * Q;  // loglik offset in d_out

typedef _Float16 h2 __attribute__((ext_vector_type(2)));

union U16 {
  uint4 u;
  h2 h[4];
};

// Per-step cross-wave traffic: 256 packed-f16 v values + broadcast shift.
struct Smem {
  alignas(16) _Float16 vb[2][Q];  // v = exp(x - shift), double buffered (1 KB)
  float sh[2];                    // state-0 value broadcast (stale shift)
  alignas(16) float afin[Q];      // final alpha for exact loglik reduce
};

__device__ __forceinline__ float wave_max64(float x) {
#pragma unroll
  for (int off = 32; off > 0; off >>= 1) x = fmaxf(x, __shfl_xor(x, off, 64));
  return x;
}
__device__ __forceinline__ float wave_sum64(float x) {
#pragma unroll
  for (int off = 32; off > 0; off >>= 1) x += __shfl_xor(x, off, 64);
  return x;
}

__device__ __forceinline__ float emit_log(const float* __restrict__ ip,
                                          const float* __restrict__ eB) {
  float acc = EPS;
#pragma unroll
  for (int s = 0; s < S; ++s) acc = fmaf(ip[s], eB[s], acc);
  return __logf(acc);
}

// Full dot for this lane's state over its 128-wide j-half.
// vrow points at this lane's half (vb + jbase). All lanes in a half read the
// same addresses -> LDS broadcast, conflict-free. 64 v_dot2_f32_f16.
__device__ __forceinline__ float matvec_f16(const h2* __restrict__ Af,
                                            const _Float16* __restrict__ vrow) {
  const uint4* v4 = (const uint4*)vrow;
  float acc[8] = {0.f, 0.f, 0.f, 0.f, 0.f, 0.f, 0.f, 0.f};
#pragma unroll
  for (int c = 0; c < 16; ++c) {
    U16 u;
    u.u = v4[c];
#pragma unroll
    for (int k = 0; k < 4; ++k) {
      const int j = 4 * c + k;
      acc[j & 7] = __builtin_amdgcn_fdot2(u.h[k], Af[j], acc[j & 7], false);
    }
  }
  float s = ((acc[0] + acc[1]) + (acc[2] + acc[3])) +
            ((acc[4] + acc[5]) + (acc[6] + acc[7]));
  return s + __shfl_xor(s, 32, 64);  // combine the two j-halves
}

// ---------------- forward ----------------
// 512 threads = 8 waves. Wave w owns states [32w, 32w+32).
// Lane l: state r = 32w + (l&31); j-half = (l<32) ? [0,128) : [128,256).
// Af[k] = {expA[jbase+2k][r], expA[jbase+2k+1][r]} packed f16 (64 VGPRs).
__device__ __forceinline__ void fwd_impl(int b, const float* __restrict__ inputs,
                                         const float* __restrict__ log_A,
                                         const float* __restrict__ log_pi,
                                         const float* __restrict__ log_B,
                                         float* __restrict__ out, Smem& sm) {
  const int tid = threadIdx.x, w = tid >> 6, lane = tid & 63;
  const int l31 = lane & 31;
  const bool lo = lane < 32;
  const int r = w * 32 + l31;
  const int jbase = lo ? 0 : 128;

  h2 Af[64];
#pragma unroll
  for (int k = 0; k < 64; ++k) {
    float x0 = __expf(log_A[(size_t)(jbase + 2 * k) * Q + r]);
    float x1 = __expf(log_A[(size_t)(jbase + 2 * k + 1) * Q + r]);
    Af[k] = h2{(_Float16)x0, (_Float16)x1};
  }
  float eB[S];
#pragma unroll
  for (int s = 0; s < S; ++s) eB[s] = __expf(log_B[r * S + s]);

  const float* __restrict__ inp_b = inputs + (size_t)b * L * S;
  float* __restrict__ post_b = out + (size_t)b * L * Q;

  // t = 0
  float alpha = emit_log(inp_b, eB) + log_pi[r];
  if (lo) post_b[r] = alpha;
  if (tid == 0) sm.sh[0] = alpha;
  __syncthreads();
  float Ssh = sm.sh[0];  // shift used building vb[0]
  if (lo) sm.vb[0][r] = (_Float16)__expf(alpha - Ssh);
  __syncthreads();

  int p = 0;
  for (int t = 1; t < L; ++t) {
    const float Snew = sm.sh[p];  // alpha_0(t-1): next shift (stale, safe)
    const float e = emit_log(inp_b + (size_t)t * S, eB);
    const float X = matvec_f16(Af, sm.vb[p] + jbase);
    alpha = __logf(X) + Ssh + e;
    if (lo) post_b[(size_t)t * Q + r] = alpha;
    if (tid == 0) sm.sh[p ^ 1] = alpha;
    if (lo) sm.vb[p ^ 1][r] = (_Float16)__expf(alpha - Snew);
    Ssh = Snew;
    __syncthreads();  // one barrier per step
    p ^= 1;
  }

  // exact loglik = logsumexp(alpha_{L-1})
  if (lo) sm.afin[r] = alpha;
  __syncthreads();
  if (w == 0) {
    float4 fa = ((const float4*)sm.afin)[lane];
    float m = fmaxf(fmaxf(fa.x, fa.y), fmaxf(fa.z, fa.w));
    m = wave_max64(m);
    float ss = __expf(fa.x - m) + __expf(fa.y - m) + __expf(fa.z - m) + __expf(fa.w - m);
    ss = wave_sum64(ss);
    if (lane == 0) out[POST + b] = __logf(ss) + m;
  }
}

// ---------------- backward ----------------
// Af[k] = {expA[r][jbase+2k], expA[r][jbase+2k+1]} (row r of A).
// MODE 0: write beta to ws (concurrent with forward). MODE 1: fused RMW.
template <int MODE>
__device__ __forceinline__ void bwd_impl(int b, const float* __restrict__ inputs,
                                         const float* __restrict__ log_A,
                                         const float* __restrict__ log_B,
                                         float* __restrict__ out,
                                         float* __restrict__ ws, Smem& sm) {
  const int tid = threadIdx.x, w = tid >> 6, lane = tid & 63;
  const int l31 = lane & 31;
  const bool lo = lane < 32;
  const int r = w * 32 + l31;
  const int jbase = lo ? 0 : 128;

  h2 Af[64];
  {
    const float* row = log_A + (size_t)r * Q + jbase;
#pragma unroll
    for (int k = 0; k < 64; ++k) {
      float x0 = __expf(row[2 * k]);
      float x1 = __expf(row[2 * k + 1]);
      Af[k] = h2{(_Float16)x0, (_Float16)x1};
    }
  }
  float eB[S];
#pragma unroll
  for (int s = 0; s < S; ++s) eB[s] = __expf(log_B[r * S + s]);

  const float* __restrict__ inp_b = inputs + (size_t)b * L * S;
  float* __restrict__ post_b = out + (size_t)b * L * Q;
  float* __restrict__ ws_b = ws + (size_t)b * L * Q;

  float ll = 0.f;
  if (MODE == 1) ll = out[POST + b];

  // beta(L-1) = 0 ; u(L-1)_j = e_j(L-1)
  float u = emit_log(inp_b + (size_t)(L - 1) * S, eB);
  if (lo) {
    if (MODE == 0) ws_b[(size_t)(L - 1) * Q + r] = 0.f;
    else post_b[(size_t)(L - 1) * Q + r] += -ll;
  }
  if (tid == 0) sm.sh[0] = u;
  __syncthreads();
  float Ssh = sm.sh[0];
  if (lo) sm.vb[0][r] = (_Float16)__expf(u - Ssh);
  __syncthreads();

  int p = 0;
  for (int t = L - 2; t >= 0; --t) {
    const float Snew = sm.sh[p];
    float aprev = 0.f;
    if (MODE == 1) aprev = post_b[(size_t)t * Q + r];
    const float e = emit_log(inp_b + (size_t)t * S, eB);
    const float X = matvec_f16(Af, sm.vb[p] + jbase);
    const float beta = __logf(X) + Ssh;
    if (lo) {
      if (MODE == 0) ws_b[(size_t)t * Q + r] = beta;
      else post_b[(size_t)t * Q + r] = aprev + beta - ll;
    }
    u = e + beta;  // u(t); harmless garbage write at t==0 (never read)
    if (tid == 0) sm.sh[p ^ 1] = u;
    if (lo) sm.vb[p ^ 1][r] = (_Float16)__expf(u - Snew);
    Ssh = Snew;
    __syncthreads();
    p ^= 1;
  }
}

// ---------------- kernels ----------------
__global__ __launch_bounds__(512, 2)
void hmm_fwdbwd(const float* __restrict__ inputs, const float* __restrict__ log_A,
                const float* __restrict__ log_pi, const float* __restrict__ log_B,
                float* __restrict__ out, float* __restrict__ ws) {
  __shared__ Smem sm;
  if (blockIdx.x < B) fwd_impl(blockIdx.x, inputs, log_A, log_pi, log_B, out, sm);
  else                bwd_impl<0>(blockIdx.x - B, inputs, log_A, log_B, out, ws, sm);
}

__global__ __launch_bounds__(256)
void hmm_combine(const float* __restrict__ ws, float* __restrict__ out) {
  const size_t idx = (size_t)blockIdx.x * 256 + threadIdx.x;  // float4 index
  const int b = (int)(idx >> 17);  // L*Q/4 = 131072 float4 per batch
  const float ll = out[POST + b];
  float4 a = ((const float4*)out)[idx];
  const float4 be = ((const float4*)ws)[idx];
  a.x += be.x - ll;
  a.y += be.y - ll;
  a.z += be.z - ll;
  a.w += be.w - ll;
  ((float4*)out)[idx] = a;
}

__global__ __launch_bounds__(512, 2)
void hmm_fwd_only(const float* __restrict__ inputs, const float* __restrict__ log_A,
                  const float* __restrict__ log_pi, const float* __restrict__ log_B,
                  float* __restrict__ out) {
  __shared__ Smem sm;
  fwd_impl(blockIdx.x, inputs, log_A, log_pi, log_B, out, sm);
}

__global__ __launch_bounds__(512, 2)
void hmm_bwd_fused(const float* __restrict__ inputs, const float* __restrict__ log_A,
                   const float* __restrict__ log_B, float* __restrict__ out) {
  __shared__ Smem sm;
  bwd_impl<1>(blockIdx.x, inputs, log_A, log_B, out, nullptr, sm);
}

}  // namespace

extern "C" void kernel_launch(void* const* d_in, const int* in_sizes, int n_in,
                              void* d_out, int out_size, void* d_ws, size_t ws_size,
                              hipStream_t stream) {
  const float* inputs = (const float*)d_in[0];
  const float* log_A  = (const float*)d_in[1];
  const float* log_pi = (const float*)d_in[2];
  const float* log_B  = (const float*)d_in[3];
  float* out = (float*)d_out;
  float* ws  = (float*)d_ws;

  if (ws_size >= POST * sizeof(float)) {
    hipLaunchKernelGGL(hmm_fwdbwd, dim3(2 * B), dim3(512), 0, stream,
                       inputs, log_A, log_pi, log_B, out, ws);
    hipLaunchKernelGGL(hmm_combine, dim3((unsigned)(POST / 4 / 256)), dim3(256), 0, stream,
                       ws, out);
  } else {
    hipLaunchKernelGGL(hmm_fwd_only, dim3(B), dim3(512), 0, stream,
                       inputs, log_A, log_pi, log_B, out);
    hipLaunchKernelGGL(hmm_bwd_fused, dim3(B), dim3(512), 0, stream,
                       inputs, log_A, log_B, out);
  }
}

// Round 5
// 1772.102 us; speedup vs baseline: 1.3420x; 1.3420x over previous
//
#include <hip/hip_runtime.h>

namespace {

constexpr int B = 64;
constexpr int L = 2048;
constexpr int Q = 256;
constexpr int S = 26;
constexpr float EPS = 1e-16f;
constexpr size_t POST = (size_t)B * L * Q;  // loglik offset in d_out

typedef _Float16 h2 __attribute__((ext_vector_type(2)));

union U16 {
  uint4 u;
  h2 h[4];
};

struct Smem {
  alignas(16) _Float16 vb[2][Q];    // scaled linear recursion vector (f16), dbuf
  alignas(16) float rowbuf[2][32];  // staged input row (26 floats), dbuf
  float sh[2];                      // state-0 anchor broadcast, dbuf
  alignas(16) float afin[Q];        // final alpha for exact loglik
};

__device__ __forceinline__ float wave_max64(float x) {
#pragma unroll
  for (int off = 32; off > 0; off >>= 1) x = fmaxf(x, __shfl_xor(x, off, 64));
  return x;
}
__device__ __forceinline__ float wave_sum64(float x) {
#pragma unroll
  for (int off = 32; off > 0; off >>= 1) x += __shfl_xor(x, off, 64);
  return x;
}

// emission dot from the LDS-staged row (broadcast b128 reads), linear output
__device__ __forceinline__ float emit_row(const float* __restrict__ rb,
                                          const float* __restrict__ eB) {
  const float4* r4 = (const float4*)rb;
  float4 c0 = r4[0], c1 = r4[1], c2 = r4[2], c3 = r4[3], c4 = r4[4], c5 = r4[5];
  float2 c6 = ((const float2*)rb)[12];
  float a0 = EPS, a1 = 0.f, a2 = 0.f, a3 = 0.f;
  a0 = fmaf(c0.x, eB[0], a0);  a1 = fmaf(c0.y, eB[1], a1);
  a2 = fmaf(c0.z, eB[2], a2);  a3 = fmaf(c0.w, eB[3], a3);
  a0 = fmaf(c1.x, eB[4], a0);  a1 = fmaf(c1.y, eB[5], a1);
  a2 = fmaf(c1.z, eB[6], a2);  a3 = fmaf(c1.w, eB[7], a3);
  a0 = fmaf(c2.x, eB[8], a0);  a1 = fmaf(c2.y, eB[9], a1);
  a2 = fmaf(c2.z, eB[10], a2); a3 = fmaf(c2.w, eB[11], a3);
  a0 = fmaf(c3.x, eB[12], a0); a1 = fmaf(c3.y, eB[13], a1);
  a2 = fmaf(c3.z, eB[14], a2); a3 = fmaf(c3.w, eB[15], a3);
  a0 = fmaf(c4.x, eB[16], a0); a1 = fmaf(c4.y, eB[17], a1);
  a2 = fmaf(c4.z, eB[18], a2); a3 = fmaf(c4.w, eB[19], a3);
  a0 = fmaf(c5.x, eB[20], a0); a1 = fmaf(c5.y, eB[21], a1);
  a2 = fmaf(c5.z, eB[22], a2); a3 = fmaf(c5.w, eB[23], a3);
  a0 = fmaf(c6.x, eB[24], a0); a1 = fmaf(c6.y, eB[25], a1);
  return (a0 + a1) + (a2 + a3);
}

// full dot for this lane's state over its 128-wide j-half (broadcast b128)
__device__ __forceinline__ float matvec_f16(const h2* __restrict__ Af,
                                            const _Float16* __restrict__ vrow) {
  const uint4* v4 = (const uint4*)vrow;
  float acc[8] = {0.f, 0.f, 0.f, 0.f, 0.f, 0.f, 0.f, 0.f};
#pragma unroll
  for (int c = 0; c < 16; ++c) {
    U16 u;
    u.u = v4[c];
#pragma unroll
    for (int k = 0; k < 4; ++k) {
      const int j = 4 * c + k;
      acc[j & 7] = __builtin_amdgcn_fdot2(u.h[k], Af[j], acc[j & 7], false);
    }
  }
  float s = ((acc[0] + acc[1]) + (acc[2] + acc[3])) +
            ((acc[4] + acc[5]) + (acc[6] + acc[7]));
  return s + __shfl_xor(s, 32, 64);  // combine the two j-halves
}

// ---------------- forward ----------------
// Linear-space recursion: v_t = X_t*e_t*gamma_t; alpha_t = log(X_t e_t) + S_{t-1}
// with S anchored each step at the (one-step-stale) state-0 alpha.
__device__ __forceinline__ void fwd_impl(int b, const float* __restrict__ inputs,
                                         const float* __restrict__ log_A,
                                         const float* __restrict__ log_pi,
                                         const float* __restrict__ log_B,
                                         float* __restrict__ out, Smem& sm) {
  const int tid = threadIdx.x, w = tid >> 6, lane = tid & 63;
  const int l31 = lane & 31;
  const bool lo = lane < 32;
  const int r = w * 32 + l31;       // owned state
  const int jbase = lo ? 0 : 128;   // j-half
  const bool stg = (w == 0) && (lane < 13);

  h2 Af[64];
#pragma unroll
  for (int k = 0; k < 64; ++k) {
    float x0 = __expf(log_A[(size_t)(jbase + 2 * k) * Q + r]);
    float x1 = __expf(log_A[(size_t)(jbase + 2 * k + 1) * Q + r]);
    Af[k] = h2{(_Float16)x0, (_Float16)x1};
  }
  float eB[S];
#pragma unroll
  for (int s = 0; s < S; ++s) eB[s] = __expf(log_B[r * S + s]);

  const float2* __restrict__ inp2 = (const float2*)(inputs + (size_t)b * L * S);
  float* __restrict__ post_b = out + (size_t)b * L * Q;

  // ---- init: stage rows 0 (into buf1) and 1 (into buf0) ----
  if (stg) {
    float2 g0 = inp2[lane];
    float2 g1 = inp2[13 + lane];
    ((float2*)sm.rowbuf[1])[lane] = g0;
    ((float2*)sm.rowbuf[0])[lane] = g1;
  }
  __syncthreads();
  float emit0 = emit_row(sm.rowbuf[1], eB);
  float alpha_cur = __logf(emit0) + log_pi[r];
  if (tid == 0) sm.sh[0] = alpha_cur;
  __syncthreads();
  float rd_prev = sm.sh[0];  // S_0 = alpha_0(0)
  if (lo) sm.vb[0][r] = (_Float16)__expf(alpha_cur - rd_prev);
  float alpha_prev = alpha_cur;  // delayed global store
  __syncthreads();

  int p = 0;
  for (int t = 1; t < L; ++t) {
    const float rd = sm.sh[p];  // alpha_{t-1}(0)
    // stage row t+1 (1 coalesced VMEM inst on wave 0)
    float2 g;
    const int tt = (t + 1 < L) ? t + 1 : L - 1;
    if (stg) g = inp2[(size_t)tt * 13 + lane];
    // delayed store of alpha_{t-1}
    if (lo) post_b[(size_t)(t - 1) * Q + r] = alpha_prev;
    // emission for t from LDS-staged row
    const float emit = emit_row(sm.rowbuf[p], eB);
    // matvec
    const float X = matvec_f16(Af, sm.vb[p] + jbase);
    const float z = X * emit;
    const float gam = __expf(rd_prev - rd);
    if (lo) sm.vb[p ^ 1][r] = (_Float16)(z * gam);
    alpha_cur = __logf(z) + rd_prev;
    if (tid == 0) sm.sh[p ^ 1] = alpha_cur;
    if (stg) ((float2*)sm.rowbuf[p ^ 1])[lane] = g;
    alpha_prev = alpha_cur;
    rd_prev = rd;
    __syncthreads();
    p ^= 1;
  }

  // epilogue: final alpha store + exact loglik
  if (lo) post_b[(size_t)(L - 1) * Q + r] = alpha_prev;
  if (lo) sm.afin[r] = alpha_prev;
  __syncthreads();
  if (w == 0) {
    float4 fa = ((const float4*)sm.afin)[lane];
    float m = fmaxf(fmaxf(fa.x, fa.y), fmaxf(fa.z, fa.w));
    m = wave_max64(m);
    float ss = __expf(fa.x - m) + __expf(fa.y - m) + __expf(fa.z - m) + __expf(fa.w - m);
    ss = wave_sum64(ss);
    if (lane == 0) out[POST + b] = __logf(ss) + m;
  }
}

// ---------------- backward ----------------
// Linear-space on g_t = e_t*exp(beta_t): w_t = raw_t*e_t*gamma; beta_t = log(raw_t)+S.
// MODE 0: beta -> ws (concurrent with fwd). MODE 1: fused RMW post += beta - ll.
template <int MODE>
__device__ __forceinline__ void bwd_impl(int b, const float* __restrict__ inputs,
                                         const float* __restrict__ log_A,
                                         const float* __restrict__ log_B,
                                         float* __restrict__ out,
                                         float* __restrict__ ws, Smem& sm) {
  const int tid = threadIdx.x, w = tid >> 6, lane = tid & 63;
  const int l31 = lane & 31;
  const bool lo = lane < 32;
  const int r = w * 32 + l31;
  const int jbase = lo ? 0 : 128;
  const bool stg = (w == 0) && (lane < 13);

  h2 Af[64];
  {
    const float* row = log_A + (size_t)r * Q + jbase;
#pragma unroll
    for (int k = 0; k < 64; ++k) {
      float x0 = __expf(row[2 * k]);
      float x1 = __expf(row[2 * k + 1]);
      Af[k] = h2{(_Float16)x0, (_Float16)x1};
    }
  }
  float eB[S];
#pragma unroll
  for (int s = 0; s < S; ++s) eB[s] = __expf(log_B[r * S + s]);

  const float2* __restrict__ inp2 = (const float2*)(inputs + (size_t)b * L * S);
  float* __restrict__ post_b = out + (size_t)b * L * Q;
  float* __restrict__ ws_b = ws + (size_t)b * L * Q;

  float ll = 0.f, aprev_hold = 0.f;
  if (MODE == 1) {
    ll = out[POST + b];
    aprev_hold = post_b[(size_t)(L - 1) * Q + r];
  }

  // ---- init: stage rows L-1 (buf1) and L-2 (buf0) ----
  if (stg) {
    float2 g0 = inp2[(size_t)(L - 1) * 13 + lane];
    float2 g1 = inp2[(size_t)(L - 2) * 13 + lane];
    ((float2*)sm.rowbuf[1])[lane] = g0;
    ((float2*)sm.rowbuf[0])[lane] = g1;
  }
  __syncthreads();
  float emitL = emit_row(sm.rowbuf[1], eB);  // e_{L-1}(r)
  if (tid == 0) sm.sh[0] = __logf(emitL);    // u_{L-1}(0) = log e_{L-1}(0)
  __syncthreads();
  float rd_prev = sm.sh[0];
  if (lo) sm.vb[0][r] = (_Float16)(emitL * __expf(-rd_prev));  // w_{L-1} = e/e(0)
  float beta_prev = 0.f;  // beta_{L-1} = 0, stored (delayed) at first loop iter
  __syncthreads();

  int p = 0;
  for (int t = L - 2; t >= 0; --t) {
    const float rd = sm.sh[p];
    float2 g;
    const int tt = (t > 0) ? t - 1 : 0;
    if (stg) g = inp2[(size_t)tt * 13 + lane];
    // delayed output for row t+1
    float anext = 0.f;
    if (MODE == 0) {
      if (lo) ws_b[(size_t)(t + 1) * Q + r] = beta_prev;
    } else {
      if (lo) post_b[(size_t)(t + 1) * Q + r] = aprev_hold + beta_prev - ll;
      anext = post_b[(size_t)t * Q + r];  // prefetch alpha_t
    }
    const float emit = emit_row(sm.rowbuf[p], eB);  // e_t(r)
    const float raw = matvec_f16(Af, sm.vb[p] + jbase);
    const float beta = __logf(raw) + rd_prev;  // beta_t(r)
    const float z = raw * emit;
    const float gam = __expf(rd_prev - rd);
    if (lo) sm.vb[p ^ 1][r] = (_Float16)(z * gam);
    if (tid == 0) sm.sh[p ^ 1] = beta + __logf(emit);  // u_t(0)
    if (stg) ((float2*)sm.rowbuf[p ^ 1])[lane] = g;
    beta_prev = beta;
    rd_prev = rd;
    if (MODE == 1) aprev_hold = anext;
    __syncthreads();
    p ^= 1;
  }

  // epilogue: row 0
  if (MODE == 0) {
    if (lo) ws_b[r] = beta_prev;
  } else {
    if (lo) post_b[r] = aprev_hold + beta_prev - ll;
  }
}

// ---------------- kernels ----------------
__global__ __launch_bounds__(512, 1)
void hmm_fwdbwd(const float* __restrict__ inputs, const float* __restrict__ log_A,
                const float* __restrict__ log_pi, const float* __restrict__ log_B,
                float* __restrict__ out, float* __restrict__ ws) {
  __shared__ Smem sm;
  if (blockIdx.x < B) fwd_impl(blockIdx.x, inputs, log_A, log_pi, log_B, out, sm);
  else                bwd_impl<0>(blockIdx.x - B, inputs, log_A, log_B, out, ws, sm);
}

__global__ __launch_bounds__(256)
void hmm_combine(const float* __restrict__ ws, float* __restrict__ out) {
  const size_t idx = (size_t)blockIdx.x * 256 + threadIdx.x;  // float4 index
  const int b = (int)(idx >> 17);  // L*Q/4 = 131072 float4 per batch
  const float ll = out[POST + b];
  float4 a = ((const float4*)out)[idx];
  const float4 be = ((const float4*)ws)[idx];
  a.x += be.x - ll;
  a.y += be.y - ll;
  a.z += be.z - ll;
  a.w += be.w - ll;
  ((float4*)out)[idx] = a;
}

__global__ __launch_bounds__(512, 1)
void hmm_fwd_only(const float* __restrict__ inputs, const float* __restrict__ log_A,
                  const float* __restrict__ log_pi, const float* __restrict__ log_B,
                  float* __restrict__ out) {
  __shared__ Smem sm;
  fwd_impl(blockIdx.x, inputs, log_A, log_pi, log_B, out, sm);
}

__global__ __launch_bounds__(512, 1)
void hmm_bwd_fused(const float* __restrict__ inputs, const float* __restrict__ log_A,
                   const float* __restrict__ log_B, float* __restrict__ out) {
  __shared__ Smem sm;
  bwd_impl<1>(blockIdx.x, inputs, log_A, log_B, out, nullptr, sm);
}

}  // namespace

extern "C" void kernel_launch(void* const* d_in, const int* in_sizes, int n_in,
                              void* d_out, int out_size, void* d_ws, size_t ws_size,
                              hipStream_t stream) {
  const float* inputs = (const float*)d_in[0];
  const float* log_A  = (const float*)d_in[1];
  const float* log_pi = (const float*)d_in[2];
  const float* log_B  = (const float*)d_in[3];
  float* out = (float*)d_out;
  float* ws  = (float*)d_ws;

  if (ws_size >= POST * sizeof(float)) {
    hipLaunchKernelGGL(hmm_fwdbwd, dim3(2 * B), dim3(512), 0, stream,
                       inputs, log_A, log_pi, log_B, out, ws);
    hipLaunchKernelGGL(hmm_combine, dim3((unsigned)(POST / 4 / 256)), dim3(256), 0, stream,
                       ws, out);
  } else {
    hipLaunchKernelGGL(hmm_fwd_only, dim3(B), dim3(512), 0, stream,
                       inputs, log_A, log_pi, log_B, out);
    hipLaunchKernelGGL(hmm_bwd_fused, dim3(B), dim3(512), 0, stream,
                       inputs, log_A, log_B, out);
  }
}